// Round 5
// baseline (229.814 us; speedup 1.0000x reference)
//
#include <hip/hip_runtime.h>

// GDAttention: B=8, S=2048, D=256, H=8.
// out[b,q,d] = (1/(q+1)) * softmax(clip(QK^T/16))·E @ Wsum^T,  Wsum[d][d'] = sum_h W_o[d][h*256+d'].
// Clip-before-softmax => no running max; softmax partials are purely additive.
//
// Structure: barrier-free k-loop, direct-global K/E fragment loads (L2-resident via
// batch<->XCD locality), 1024 blocks x 4 waves, 4 blocks/CU (16 waves/CU = 4/SIMD).

typedef __attribute__((ext_vector_type(8))) short short8;   // 8 x bf16 (4 VGPRs) MFMA frag
typedef __attribute__((ext_vector_type(4))) float f32x4;    // MFMA 16x16 accumulator

__device__ __forceinline__ unsigned short f2b(float x) {    // f32 -> bf16 (round-to-nearest-even)
  unsigned u = __builtin_bit_cast(unsigned, x);
  u = (u + 0x7fffu + ((u >> 16) & 1u)) >> 16;
  return (unsigned short)u;
}

// ---------- pre-pass 1: p (f32 [8][2049][256]) -> bf16, same layout ----------
__global__ void cvt_p_kernel(const float* __restrict__ src, unsigned short* __restrict__ dst) {
  size_t t = (size_t)blockIdx.x * 256 + threadIdx.x;  // 524544 threads, 8 elems each
  const float4* s = (const float4*)(src + t * 8);
  float4 a = s[0], b = s[1];
  short8 o;
  o[0] = (short)f2b(a.x); o[1] = (short)f2b(a.y); o[2] = (short)f2b(a.z); o[3] = (short)f2b(a.w);
  o[4] = (short)f2b(b.x); o[5] = (short)f2b(b.y); o[6] = (short)f2b(b.z); o[7] = (short)f2b(b.w);
  *(short8*)(dst + t * 8) = o;
}

// ---------- pre-pass 2: e (f32 [8][2048][256]) -> B-fragment-ready bf16 ----------
// chunk (b,kt) elem ((d0*64 + lane)*8 + i) = e[b][kt*32 + (lane>>4)*8 + i][d0*16 + (lane&15)]
// => in-loop E frag loads are lane-consecutive (1KB contiguous per wave instruction).
__global__ void perm_e_kernel(const float* __restrict__ e, unsigned short* __restrict__ dst) {
  size_t t = (size_t)blockIdx.x * 256 + threadIdx.x;  // 524288 threads
  int lane = (int)(t & 63);
  int d0 = (int)((t >> 6) & 15);
  int kt = (int)((t >> 10) & 63);
  int b = (int)(t >> 16);
  int g = lane >> 4, l = lane & 15;
  const float* s = e + ((size_t)b * 2048 + kt * 32 + g * 8) * 256 + d0 * 16 + l;
  short8 o;
#pragma unroll
  for (int i = 0; i < 8; ++i) o[i] = (short)f2b(s[(size_t)i * 256]);
  *(short8*)(dst + t * 8) = o;
}

// ---------- pre-pass 3: fold W_o over heads -> bf16 Wsum [256][256] (coalesced) ----------
__global__ void fold_w_kernel(const float* __restrict__ w, unsigned short* __restrict__ dst) {
  int d = blockIdx.x;    // 256
  int c = threadIdx.x;   // 256
  const float* row = w + (size_t)d * 2048 + c;
  float s = 0.f;
#pragma unroll
  for (int h = 0; h < 8; ++h) s += row[h * 256];
  dst[d * 256 + c] = f2b(s);
}

// ---------- main kernel ----------
// grid = 1024: b = bid&7 (batch<->XCD via round-robin bid%8), j = bid>>3 in 0..127,
// t16 = j<64 ? j : 191-j  (pairs heavy+light q-tiles on the same CU under the usual
// within-XCD block->CU striding; worst case is only mild imbalance).
// Block: one 16-row q-tile, 4 waves = kv-parity 0..3. K-loop has NO barriers: K/E frags
// come straight from global (L2), P round-trip uses per-wave-private LDS.
// LDS map: [0,16384) combine buf (f32x4 frag-order); [16384,24832) PY bf16 [16][264]
//          (k-loop overlay: per-wave P tiles [16][40] ushort at 16384+wave*1280);
//          [24832,25024) dsum combine [3][16] f32.
#define SMEM_BYTES 25088

__global__ __launch_bounds__(256, 4) void attn_main_kernel(const unsigned short* __restrict__ pbf,
                                                           const unsigned short* __restrict__ eperm,
                                                           const unsigned short* __restrict__ wsum,
                                                           float* __restrict__ out) {
  __shared__ char smem[SMEM_BYTES];
  const int b = blockIdx.x & 7;
  const int j0 = blockIdx.x >> 3;
  const int t16 = (j0 < 64) ? j0 : 191 - j0;
  const int qbase = t16 * 16;
  const int nkt = (t16 >> 1) + 1;       // causal k-tiles (32 wide) for rows qbase..qbase+15
  const int wave = threadIdx.x >> 6;    // kv parity 0..3
  const int lane = threadIdx.x & 63;
  const int g = lane >> 4;
  const int l = lane & 15;
  const f32x4 zero = {0.f, 0.f, 0.f, 0.f};

  // Q frags in registers: qf[kc][i] = Q[qbase + l][kc*32 + g*8 + i]  (q = p[:,1:,:])
  short8 qf[8];
  {
    const unsigned short* qrow = pbf + ((size_t)b * 2049 + qbase + l + 1) * 256;
#pragma unroll
    for (int kc = 0; kc < 8; ++kc) qf[kc] = *(const short8*)(qrow + kc * 32 + g * 8);
  }

  f32x4 yacc[16];
#pragma unroll
  for (int i = 0; i < 16; ++i) yacc[i] = zero;
  float dsum[4] = {0.f, 0.f, 0.f, 0.f};

  unsigned short* pp = (unsigned short*)(smem + 16384 + wave * 1280);  // [16][40] private
  const unsigned short* kpool = pbf + (size_t)b * 2049 * 256;
  const unsigned short* epool = eperm + (size_t)b * 64 * 8192 + (size_t)lane * 8;

  for (int kt = wave; kt < nkt; kt += 4) {
    // QK^T: A=Q, B=K^T read direct from global (16 rows x 64B per instr, L2-hit)
    f32x4 sacc0 = zero, sacc1 = zero;
    const unsigned short* kb = kpool + (size_t)kt * 32 * 256;
#pragma unroll
    for (int kc = 0; kc < 8; ++kc) {
      short8 k0 = *(const short8*)(kb + (size_t)l * 256 + kc * 32 + g * 8);
      short8 k1 = *(const short8*)(kb + (size_t)(16 + l) * 256 + kc * 32 + g * 8);
      sacc0 = __builtin_amdgcn_mfma_f32_16x16x32_bf16(qf[kc], k0, sacc0, 0, 0, 0);
      sacc1 = __builtin_amdgcn_mfma_f32_16x16x32_bf16(qf[kc], k1, sacc1, 0, 0, 0);
    }
    // weights: w = exp(clip(s/16)), causal-masked; additive partials (no max tracking)
#pragma unroll
    for (int n0 = 0; n0 < 2; ++n0) {
      const int kg = kt * 32 + n0 * 16 + l;
      const f32x4 sv = n0 ? sacc1 : sacc0;
#pragma unroll
      for (int jj = 0; jj < 4; ++jj) {
        float s = sv[jj] * 0.0625f;
        s = fminf(fmaxf(s, -10.f), 10.f);
        const int qg = qbase + g * 4 + jj;
        float w = (kg <= qg) ? __expf(s) : 0.f;
        dsum[jj] += w;
        pp[(g * 4 + jj) * 40 + n0 * 16 + l] = f2b(w);  // private P [16][40]
      }
    }
    // PV: A=P (per-wave LDS round-trip), B=E direct from global (1KB contiguous/instr)
    short8 af = *(const short8*)((const unsigned short*)pp + l * 40 + g * 8);
    const unsigned short* eb = epool + (size_t)kt * 8192;
#pragma unroll
    for (int d0 = 0; d0 < 16; ++d0) {
      short8 ef = *(const short8*)(eb + d0 * 512);
      yacc[d0] = __builtin_amdgcn_mfma_f32_16x16x32_bf16(af, ef, yacc[d0], 0, 0, 0);
    }
  }

  // row-sum of dsum across the 16 l-lanes (stays within each 16-lane group)
#pragma unroll
  for (int jj = 0; jj < 4; ++jj) {
    float v = dsum[jj];
    v += __shfl_xor(v, 1);
    v += __shfl_xor(v, 2);
    v += __shfl_xor(v, 4);
    v += __shfl_xor(v, 8);
    dsum[jj] = v;
  }
  float* dbuf = (float*)(smem + 24832);  // [3][16]
  if (wave != 0 && l == 0) {
#pragma unroll
    for (int jj = 0; jj < 4; ++jj) dbuf[(wave - 1) * 16 + g * 4 + jj] = dsum[jj];
  }

  // combine the 4 parity partials: serial rmw through one 16KB frag-order buffer
  f32x4* bufv = (f32x4*)smem;  // index d0*64+lane (lane-linear b128, conflict-free)
  __syncthreads();
  if (wave == 1) {
#pragma unroll
    for (int d0 = 0; d0 < 16; ++d0) bufv[d0 * 64 + lane] = yacc[d0];
  }
  __syncthreads();
  if (wave == 0) {
#pragma unroll
    for (int d0 = 0; d0 < 16; ++d0) yacc[d0] += bufv[d0 * 64 + lane];
  }
  __syncthreads();
  if (wave == 2) {
#pragma unroll
    for (int d0 = 0; d0 < 16; ++d0) bufv[d0 * 64 + lane] = yacc[d0];
  }
  __syncthreads();
  if (wave == 0) {
#pragma unroll
    for (int d0 = 0; d0 < 16; ++d0) yacc[d0] += bufv[d0 * 64 + lane];
  }
  __syncthreads();
  if (wave == 3) {
#pragma unroll
    for (int d0 = 0; d0 < 16; ++d0) bufv[d0 * 64 + lane] = yacc[d0];
  }
  __syncthreads();
  unsigned short* py = (unsigned short*)(smem + 16384);  // [16][264] bf16 (overlays P)
  if (wave == 0) {
    float inv[4];
#pragma unroll
    for (int jj = 0; jj < 4; ++jj) {
      float dtot = dsum[jj] + dbuf[g * 4 + jj] + dbuf[16 + g * 4 + jj] + dbuf[32 + g * 4 + jj];
      const int qg = qbase + g * 4 + jj;
      inv[jj] = 1.f / (dtot * (float)(qg + 1));  // softmax denom * row_scale
    }
#pragma unroll
    for (int d0 = 0; d0 < 16; ++d0) {
      f32x4 yt = yacc[d0] + bufv[d0 * 64 + lane];
#pragma unroll
      for (int jj = 0; jj < 4; ++jj)
        py[(g * 4 + jj) * 264 + d0 * 16 + l] = f2b(yt[jj] * inv[jj]);
    }
  }
  __syncthreads();

  // epilogue: out[q][d] = sum_d' y_norm[q][d'] * Wsum[d][d']; wave handles d0 = wave*4..+4
  {
    f32x4 oacc[4];
#pragma unroll
    for (int i = 0; i < 4; ++i) oacc[i] = zero;
#pragma unroll
    for (int kc = 0; kc < 8; ++kc) {
      short8 a2 = *(const short8*)(py + l * 264 + kc * 32 + g * 8);
#pragma unroll
      for (int dd = 0; dd < 4; ++dd) {
        short8 wf =
            *(const short8*)(wsum + (size_t)((wave * 4 + dd) * 16 + l) * 256 + kc * 32 + g * 8);
        oacc[dd] = __builtin_amdgcn_mfma_f32_16x16x32_bf16(a2, wf, oacc[dd], 0, 0, 0);
      }
    }
#pragma unroll
    for (int dd = 0; dd < 4; ++dd) {
#pragma unroll
      for (int jj = 0; jj < 4; ++jj) {
        const int qg = qbase + g * 4 + jj;
        const int d = (wave * 4 + dd) * 16 + l;
        out[((size_t)b * 2048 + qg) * 256 + d] = oacc[dd][jj];
      }
    }
  }
}

extern "C" void kernel_launch(void* const* d_in, const int* in_sizes, int n_in, void* d_out,
                              int out_size, void* d_ws, size_t ws_size, hipStream_t stream) {
  (void)in_sizes; (void)n_in; (void)out_size; (void)ws_size;
  const float* e = (const float*)d_in[0];    // [8][2048][256]
  const float* p = (const float*)d_in[1];    // [8][2049][256]
  const float* Wo = (const float*)d_in[2];   // [256][2048]
  float* out = (float*)d_out;                // [8][2048][256] f32

  unsigned short* pbf = (unsigned short*)d_ws;                        // 8,392,704 B
  unsigned short* eperm = (unsigned short*)((char*)d_ws + 8392704);   // 8,388,608 B
  unsigned short* wsum = (unsigned short*)((char*)d_ws + 16781312);   // 131,072 B

  hipLaunchKernelGGL(cvt_p_kernel, dim3(2049), dim3(256), 0, stream, p, pbf);
  hipLaunchKernelGGL(perm_e_kernel, dim3(2048), dim3(256), 0, stream, e, eperm);
  hipLaunchKernelGGL(fold_w_kernel, dim3(256), dim3(256), 0, stream, Wo, wsum);
  hipLaunchKernelGGL(attn_main_kernel, dim3(1024), dim3(256), 0, stream, pbf, eperm, wsum, out);
}

// Round 6
// 149.607 us; speedup vs baseline: 1.5361x; 1.5361x over previous
//
#include <hip/hip_runtime.h>

// GDAttention: B=8, S=2048, D=256, H=8.
// out[b,q,d] = (1/(q+1)) * softmax(clip(QK^T/16))·E @ Wsum^T,  Wsum[d][d'] = sum_h W_o[d][h*256+d'].
// Clip-before-softmax => no running max; softmax partials are purely additive.
//
// R6: software-pipelined barrier-free k-loop. K and E both pre-permuted to fragment-linear
// (1KB contiguous per wave load); kf/ef tiles held in registers, next tile's loads issued
// behind the phase that consumes the current one. launch_bounds(256,2) -> ~250 VGPR,
// 2 blocks/CU x 4 waves = 8 waves/CU. L2-resident via batch<->XCD locality (b = bid&7).

typedef __attribute__((ext_vector_type(8))) short short8;   // 8 x bf16 (4 VGPRs) MFMA frag
typedef __attribute__((ext_vector_type(4))) float f32x4;    // MFMA 16x16 accumulator

__device__ __forceinline__ unsigned short f2b(float x) {    // f32 -> bf16 (round-to-nearest-even)
  unsigned u = __builtin_bit_cast(unsigned, x);
  u = (u + 0x7fffu + ((u >> 16) & 1u)) >> 16;
  return (unsigned short)u;
}

// ---------- pre-pass 1: p (f32 [8][2049][256]) -> bf16, same layout (Q source) ----------
__global__ void cvt_p_kernel(const float* __restrict__ src, unsigned short* __restrict__ dst) {
  size_t t = (size_t)blockIdx.x * 256 + threadIdx.x;  // 524544 threads, 8 elems each
  const float4* s = (const float4*)(src + t * 8);
  float4 a = s[0], b = s[1];
  short8 o;
  o[0] = (short)f2b(a.x); o[1] = (short)f2b(a.y); o[2] = (short)f2b(a.z); o[3] = (short)f2b(a.w);
  o[4] = (short)f2b(b.x); o[5] = (short)f2b(b.y); o[6] = (short)f2b(b.z); o[7] = (short)f2b(b.w);
  *(short8*)(dst + t * 8) = o;
}

// ---------- pre-pass 2: e -> B-fragment-ready bf16 ----------
// chunk (b,kt) elem ((d0*64 + lane)*8 + i) = e[b][kt*32 + (lane>>4)*8 + i][d0*16 + (lane&15)]
__global__ void perm_e_kernel(const float* __restrict__ e, unsigned short* __restrict__ dst) {
  size_t t = (size_t)blockIdx.x * 256 + threadIdx.x;  // 524288 threads
  int lane = (int)(t & 63);
  int d0 = (int)((t >> 6) & 15);
  int kt = (int)((t >> 10) & 63);
  int b = (int)(t >> 16);
  int g = lane >> 4, l = lane & 15;
  const float* s = e + ((size_t)b * 2048 + kt * 32 + g * 8) * 256 + d0 * 16 + l;
  short8 o;
#pragma unroll
  for (int i = 0; i < 8; ++i) o[i] = (short)f2b(s[(size_t)i * 256]);
  *(short8*)(dst + t * 8) = o;
}

// ---------- pre-pass 2b: K (= p[:, :-1, :]) -> B-fragment-ready bf16 ----------
// chunk (b,kt) elem (((kc*2+n0)*64 + lane)*8 + i) = p[b][kt*32 + n0*16 + (lane&15)][kc*32 + (lane>>4)*8 + i]
// => in-loop K frag loads are 1KB contiguous per wave instruction (like E).
__global__ void perm_k_kernel(const float* __restrict__ p, unsigned short* __restrict__ dst) {
  size_t t = (size_t)blockIdx.x * 256 + threadIdx.x;  // 524288 threads
  int lane = (int)(t & 63);
  int idx = (int)((t >> 6) & 15);  // kc*2 + n0
  int kt = (int)((t >> 10) & 63);
  int b = (int)(t >> 16);
  int kc = idx >> 1, n0 = idx & 1;
  int g = lane >> 4, l = lane & 15;
  const float* s = p + ((size_t)b * 2049 + kt * 32 + n0 * 16 + l) * 256 + kc * 32 + g * 8;
  float4 a = *(const float4*)s;
  float4 c = *(const float4*)(s + 4);
  short8 o;
  o[0] = (short)f2b(a.x); o[1] = (short)f2b(a.y); o[2] = (short)f2b(a.z); o[3] = (short)f2b(a.w);
  o[4] = (short)f2b(c.x); o[5] = (short)f2b(c.y); o[6] = (short)f2b(c.z); o[7] = (short)f2b(c.w);
  *(short8*)(dst + t * 8) = o;
}

// ---------- pre-pass 3: fold W_o over heads -> bf16 Wsum [256][256] (coalesced) ----------
__global__ void fold_w_kernel(const float* __restrict__ w, unsigned short* __restrict__ dst) {
  int d = blockIdx.x;    // 256
  int c = threadIdx.x;   // 256
  const float* row = w + (size_t)d * 2048 + c;
  float s = 0.f;
#pragma unroll
  for (int h = 0; h < 8; ++h) s += row[h * 256];
  dst[d * 256 + c] = f2b(s);
}

// ---------- main kernel ----------
// grid = 1024: b = bid&7 (batch<->XCD via round-robin bid%8), j = bid>>3 in 0..127,
// t16 = j<64 ? j : 191-j. Block: one 16-row q-tile, 4 waves = kv-parity 0..3.
// Barrier-free k-loop; kf/ef register tiles software-pipelined one iteration ahead.
// LDS map: [0,16384) combine buf (f32x4 frag-order); [16384,24832) PY bf16 [16][264]
//          (k-loop overlay: per-wave P tiles [16][40] ushort at 16384+wave*1280);
//          [24832,25024) dsum combine [3][16] f32.
#define SMEM_BYTES 25088

__global__ __launch_bounds__(256, 2) void attn_main_kernel(const unsigned short* __restrict__ pbf,
                                                           const unsigned short* __restrict__ kperm,
                                                           const unsigned short* __restrict__ eperm,
                                                           const unsigned short* __restrict__ wsum,
                                                           float* __restrict__ out) {
  __shared__ char smem[SMEM_BYTES];
  const int b = blockIdx.x & 7;
  const int j0 = blockIdx.x >> 3;
  const int t16 = (j0 < 64) ? j0 : 191 - j0;
  const int qbase = t16 * 16;
  const int nkt = (t16 >> 1) + 1;       // causal k-tiles (32 wide) for rows qbase..qbase+15
  const int wave = threadIdx.x >> 6;    // kv parity 0..3
  const int lane = threadIdx.x & 63;
  const int g = lane >> 4;
  const int l = lane & 15;
  const f32x4 zero = {0.f, 0.f, 0.f, 0.f};

  // Q frags in registers: qf[kc][i] = Q[qbase + l][kc*32 + g*8 + i]  (q = p[:,1:,:])
  short8 qf[8];
  {
    const unsigned short* qrow = pbf + ((size_t)b * 2049 + qbase + l + 1) * 256;
#pragma unroll
    for (int kc = 0; kc < 8; ++kc) qf[kc] = *(const short8*)(qrow + kc * 32 + g * 8);
  }

  f32x4 yacc[16];
#pragma unroll
  for (int i = 0; i < 16; ++i) yacc[i] = zero;
  float dsum[4] = {0.f, 0.f, 0.f, 0.f};

  unsigned short* pp = (unsigned short*)(smem + 16384 + wave * 1280);  // [16][40] private
  const unsigned short* kpool = kperm + (size_t)b * 64 * 8192 + (size_t)lane * 8;
  const unsigned short* epool = eperm + (size_t)b * 64 * 8192 + (size_t)lane * 8;

  short8 kf[16], ef[16];  // current K/E tiles in registers (128 VGPRs)
  if (wave < nkt) {
    const unsigned short* kb = kpool + (size_t)wave * 8192;
    const unsigned short* eb = epool + (size_t)wave * 8192;
#pragma unroll
    for (int i = 0; i < 16; ++i) kf[i] = *(const short8*)(kb + i * 512);
#pragma unroll
    for (int i = 0; i < 16; ++i) ef[i] = *(const short8*)(eb + i * 512);
  }

  for (int kt = wave; kt < nkt; kt += 4) {
    const int ktn = kt + 4;
    // QK^T: A=Q, B=K frags already resident
    f32x4 sacc0 = zero, sacc1 = zero;
#pragma unroll
    for (int kc = 0; kc < 8; ++kc) {
      sacc0 = __builtin_amdgcn_mfma_f32_16x16x32_bf16(qf[kc], kf[kc * 2 + 0], sacc0, 0, 0, 0);
      sacc1 = __builtin_amdgcn_mfma_f32_16x16x32_bf16(qf[kc], kf[kc * 2 + 1], sacc1, 0, 0, 0);
    }
    // prefetch next K tile (flies under exp + PV)
    if (ktn < nkt) {
      const unsigned short* kb = kpool + (size_t)ktn * 8192;
#pragma unroll
      for (int i = 0; i < 16; ++i) kf[i] = *(const short8*)(kb + i * 512);
    }
    // weights: w = exp(clip(s/16)), causal-masked; additive partials (no max tracking)
#pragma unroll
    for (int n0 = 0; n0 < 2; ++n0) {
      const int kg = kt * 32 + n0 * 16 + l;
      const f32x4 sv = n0 ? sacc1 : sacc0;
#pragma unroll
      for (int jj = 0; jj < 4; ++jj) {
        float s = sv[jj] * 0.0625f;
        s = fminf(fmaxf(s, -10.f), 10.f);
        const int qg = qbase + g * 4 + jj;
        float w = (kg <= qg) ? __expf(s) : 0.f;
        dsum[jj] += w;
        pp[(g * 4 + jj) * 40 + n0 * 16 + l] = f2b(w);  // private P [16][40]
      }
    }
    // PV: A=P (per-wave LDS round-trip), B=E frags already resident
    short8 af = *(const short8*)((const unsigned short*)pp + l * 40 + g * 8);
#pragma unroll
    for (int d0 = 0; d0 < 16; ++d0)
      yacc[d0] = __builtin_amdgcn_mfma_f32_16x16x32_bf16(af, ef[d0], yacc[d0], 0, 0, 0);
    // prefetch next E tile (flies under next iteration's QK)
    if (ktn < nkt) {
      const unsigned short* eb = epool + (size_t)ktn * 8192;
#pragma unroll
      for (int i = 0; i < 16; ++i) ef[i] = *(const short8*)(eb + i * 512);
    }
  }

  // row-sum of dsum across the 16 l-lanes (stays within each 16-lane group)
#pragma unroll
  for (int jj = 0; jj < 4; ++jj) {
    float v = dsum[jj];
    v += __shfl_xor(v, 1);
    v += __shfl_xor(v, 2);
    v += __shfl_xor(v, 4);
    v += __shfl_xor(v, 8);
    dsum[jj] = v;
  }
  float* dbuf = (float*)(smem + 24832);  // [3][16]
  if (wave != 0 && l == 0) {
#pragma unroll
    for (int jj = 0; jj < 4; ++jj) dbuf[(wave - 1) * 16 + g * 4 + jj] = dsum[jj];
  }

  // combine the 4 parity partials: serial rmw through one 16KB frag-order buffer
  f32x4* bufv = (f32x4*)smem;  // index d0*64+lane (lane-linear b128, conflict-free)
  __syncthreads();
  if (wave == 1) {
#pragma unroll
    for (int d0 = 0; d0 < 16; ++d0) bufv[d0 * 64 + lane] = yacc[d0];
  }
  __syncthreads();
  if (wave == 0) {
#pragma unroll
    for (int d0 = 0; d0 < 16; ++d0) yacc[d0] += bufv[d0 * 64 + lane];
  }
  __syncthreads();
  if (wave == 2) {
#pragma unroll
    for (int d0 = 0; d0 < 16; ++d0) bufv[d0 * 64 + lane] = yacc[d0];
  }
  __syncthreads();
  if (wave == 0) {
#pragma unroll
    for (int d0 = 0; d0 < 16; ++d0) yacc[d0] += bufv[d0 * 64 + lane];
  }
  __syncthreads();
  if (wave == 3) {
#pragma unroll
    for (int d0 = 0; d0 < 16; ++d0) bufv[d0 * 64 + lane] = yacc[d0];
  }
  __syncthreads();
  unsigned short* py = (unsigned short*)(smem + 16384);  // [16][264] bf16 (overlays P)
  if (wave == 0) {
    float inv[4];
#pragma unroll
    for (int jj = 0; jj < 4; ++jj) {
      float dtot = dsum[jj] + dbuf[g * 4 + jj] + dbuf[16 + g * 4 + jj] + dbuf[32 + g * 4 + jj];
      const int qg = qbase + g * 4 + jj;
      inv[jj] = 1.f / (dtot * (float)(qg + 1));  // softmax denom * row_scale
    }
#pragma unroll
    for (int d0 = 0; d0 < 16; ++d0) {
      f32x4 yt = yacc[d0] + bufv[d0 * 64 + lane];
#pragma unroll
      for (int jj = 0; jj < 4; ++jj)
        py[(g * 4 + jj) * 264 + d0 * 16 + l] = f2b(yt[jj] * inv[jj]);
    }
  }
  __syncthreads();

  // epilogue: out[q][d] = sum_d' y_norm[q][d'] * Wsum[d][d']; wave handles d0 = wave*4..+4
  {
    f32x4 oacc[4];
#pragma unroll
    for (int i = 0; i < 4; ++i) oacc[i] = zero;
#pragma unroll
    for (int kc = 0; kc < 8; ++kc) {
      short8 a2 = *(const short8*)(py + l * 264 + kc * 32 + g * 8);
#pragma unroll
      for (int dd = 0; dd < 4; ++dd) {
        short8 wf =
            *(const short8*)(wsum + (size_t)((wave * 4 + dd) * 16 + l) * 256 + kc * 32 + g * 8);
        oacc[dd] = __builtin_amdgcn_mfma_f32_16x16x32_bf16(a2, wf, oacc[dd], 0, 0, 0);
      }
    }
#pragma unroll
    for (int dd = 0; dd < 4; ++dd) {
#pragma unroll
      for (int jj = 0; jj < 4; ++jj) {
        const int qg = qbase + g * 4 + jj;
        const int d = (wave * 4 + dd) * 16 + l;
        out[((size_t)b * 2048 + qg) * 256 + d] = oacc[dd][jj];
      }
    }
  }
}

extern "C" void kernel_launch(void* const* d_in, const int* in_sizes, int n_in, void* d_out,
                              int out_size, void* d_ws, size_t ws_size, hipStream_t stream) {
  (void)in_sizes; (void)n_in; (void)out_size; (void)ws_size;
  const float* e = (const float*)d_in[0];    // [8][2048][256]
  const float* p = (const float*)d_in[1];    // [8][2049][256]
  const float* Wo = (const float*)d_in[2];   // [256][2048]
  float* out = (float*)d_out;                // [8][2048][256] f32

  unsigned short* pbf = (unsigned short*)d_ws;                        // 8,392,704 B
  unsigned short* eperm = (unsigned short*)((char*)d_ws + 8392704);   // 8,388,608 B
  unsigned short* kperm = (unsigned short*)((char*)d_ws + 16781312);  // 8,388,608 B
  unsigned short* wsum = (unsigned short*)((char*)d_ws + 25169920);   // 131,072 B

  hipLaunchKernelGGL(cvt_p_kernel, dim3(2049), dim3(256), 0, stream, p, pbf);
  hipLaunchKernelGGL(perm_e_kernel, dim3(2048), dim3(256), 0, stream, e, eperm);
  hipLaunchKernelGGL(perm_k_kernel, dim3(2048), dim3(256), 0, stream, p, kperm);
  hipLaunchKernelGGL(fold_w_kernel, dim3(256), dim3(256), 0, stream, Wo, wsum);
  hipLaunchKernelGGL(attn_main_kernel, dim3(1024), dim3(256), 0, stream, pbf, kperm, eperm, wsum,
                     out);
}